// Round 8
// baseline (96.763 us; speedup 1.0000x reference)
//
#include <hip/hip_runtime.h>

// StericClashConstraint: N=16384 pts [N,3] fp32.
// out[0..3N-1] = pos passthrough; out[3N] = mean(max(1-dist,0), diag=0) * 0.02
//
// Round 14: 2 dispatches - scatter+pair fused with a HOMEBREW grid barrier.
// Budget from R12/R13 counters: fill poison 40us (immovable) + ~27us fixed
// graph/launch floor + ~15us controllable (kernels ~10 + dispatch gaps ~5).
// R12 proved the fused phases are correct but cg::grid.sync() costs ~35us
// (system-scope spin). The barrier we need is cheap: 256 same-address
// agent-scope arrivals (sub-us; the finalize already does 256 same-address
// atomics every round) + acquire spin + threadfence wb/inv on each side
// (per-XCD L2s hold stale fill/remote lines -> inv required before reading
// jt4s written by other XCDs).
//  k1 prep:  copy + per-block LDS z-hist -> partials; pack (cell,rank) in crk;
//            zero acc/cnt/bar.   [kernel boundary = hist->scan sync, free]
//  k2 fused: every block redundantly scans the 64x256 partials (R13-proven),
//            scatters its 64 points atomic-free, computes its group's jend
//            from the in-LDS scan (jendArr eliminated), homebrew barrier,
//            then the R13 pair body BIT-IDENTICAL, then acc/cnt finalize.
// Deadlock safety: 256 blocks x 4 waves, ~7KB LDS, low VGPR -> 1 block/CU
// with 8x residency headroom; all co-resident. Replay safety: bar zeroed by
// prep each replay (stream-ordered before k2).
// Bins: 256 x width 1/4 (z*4 exact in fp32), MARGIN=6 -> excluded pairs have
// dz > 1.25 > 1 exactly; clamped edge bins only widen windows (conservative).

constexpr int   N     = 16384;
constexpr int   BLOCK = 256;            // 4 waves
constexpr int   GSZ   = 512;            // i-group size
constexpr int   IPT   = GSZ / BLOCK;    // 2 i's per thread
constexpr int   NG    = N / GSZ;        // 32 i-groups
constexpr int   F     = 8;              // j-segments per group
constexpr int   NB    = NG * F;         // 256 fused blocks = 1/CU
constexpr int   QB    = 4;              // columns per unrolled chunk
constexpr int   NBINS = 256;            // z-bins, width 1/4, covering [-32,32)
constexpr float BINW_INV = 4.0f;        // *4 exact in fp32
constexpr int   MARGIN = 6;             // cell_j >= cell_i+6 => dz > 1.25 > 1
constexpr int   CH    = 288;            // columns staged per LDS chunk
constexpr int   NHB   = N / BLOCK;      // 64 prep blocks

__device__ __forceinline__ int zcell(float z) {
    int c = (int)floorf(z * BINW_INV) + NBINS / 2;
    return min(max(c, 0), NBINS - 1);
}

// ---- k1: passthrough + per-block partial hist + (cell,rank) pack -----------
__global__ void __launch_bounds__(BLOCK)
prep_kernel(const float* __restrict__ pos, float* __restrict__ out,
            unsigned int* __restrict__ histPart, unsigned int* __restrict__ crk,
            float* __restrict__ acc, unsigned int* __restrict__ cnt,
            unsigned int* __restrict__ bar) {
    __shared__ unsigned int lh[NBINS];
    const int b = blockIdx.x, t = threadIdx.x;
    const int gt = b * BLOCK + t;                     // 0..16383
    lh[t] = 0u;                                       // NBINS == BLOCK
    if (gt == 0) { *acc = 0.0f; *cnt = 0u; *bar = 0u; }   // replay-safe init
    __syncthreads();
    if (gt < (N * 3) / 4) {
        reinterpret_cast<float4*>(out)[gt] = reinterpret_cast<const float4*>(pos)[gt];
    }
    const float z = pos[3 * gt + 2];
    const int cell = zcell(z);
    const unsigned int rank = atomicAdd(&lh[cell], 1u);   // rank in (block,cell)
    crk[gt] = (unsigned int)cell | (rank << 16);
    __syncthreads();
    histPart[b * NBINS + t] = lh[t];
}

// ---- pair inner loop (R13 verbatim) ----------------------------------------
template <bool MASKED>
__device__ __forceinline__ float cols(const float4* __restrict__ jsm,
                                      int clen, int jbase, int i0,
                                      const float (&xi2)[IPT], const float (&yi2)[IPT],
                                      const float (&zi2)[IPT], const float (&sqi)[IPT]) {
    float s = 0.0f;
    for (int c = 0; c < clen; c += QB) {              // sentinel pad covers overrun
        #pragma unroll
        for (int u = 0; u < QB; ++u) {
            const float4 pj = jsm[c + u];             // uniform addr -> broadcast
            const int jq = jbase + c + u;
            #pragma unroll
            for (int k = 0; k < IPT; ++k) {
                float d = fmaf(xi2[k], pj.x, pj.w);
                d = fmaf(yi2[k], pj.y, d);
                d = fmaf(zi2[k], pj.z, d);                     // sq_j - 2*dot
                const float d2 = fmaxf(d + sqi[k], 0.0f);      // + sq_i, clamp
                float w = 1.0f - __builtin_amdgcn_sqrtf(d2);   // 1 - dist
                w = fmaxf(w, 0.0f);                            // clamp(min=0)
                if (MASKED) w = (jq > i0 + k * BLOCK) ? w : 0.0f;   // j>i only
                s += w;
            }
        }
    }
    return s;
}

// ---- k2: redundant scan + atomic-free scatter + barrier + pair -------------
__global__ void __launch_bounds__(BLOCK)
fused_kernel(const float* __restrict__ pos, const unsigned int* __restrict__ histPart,
             const unsigned int* __restrict__ crk, float4* __restrict__ jt4s,
             unsigned int* __restrict__ bar, float* __restrict__ out,
             float* __restrict__ acc, unsigned int* __restrict__ cnt) {
    __shared__ int sm[NBINS];
    __shared__ int beforeB[NBINS];
    __shared__ float4 jsm[CH + QB];
    __shared__ float wsum[BLOCK / 64];
    const int b = blockIdx.x, t = threadIdx.x;

    // --- scan (every block, redundant; R13-proven) ---
    const int pb = b >> 2;                 // prep-block owning my 64 scatter pts
    int v = 0, bef = 0;
    #pragma unroll 8
    for (int p = 0; p < NHB; ++p) {        // coalesced L2 reads
        const int hv = (int)histPart[p * NBINS + t];
        if (p == pb) bef = v;              // sum over prep-blocks < pb
        v += hv;
    }
    sm[t] = v; beforeB[t] = bef;
    __syncthreads();
    for (int off = 1; off < NBINS; off <<= 1) {        // Hillis-Steele inclusive
        const int a = (t >= off) ? sm[t - off] : 0;
        __syncthreads();
        sm[t] += a;
        __syncthreads();
    }

    // --- scatter my 64 points, no atomics ---
    if (t < 64) {
        const int gt = b * 64 + t;                     // gt>>8 == pb for all 64
        const unsigned int cr = crk[gt];
        const int cell = (int)(cr & 0xffffu);
        const int rank = (int)(cr >> 16);
        const int ex   = (cell > 0) ? sm[cell - 1] : 0;
        const int dst  = ex + beforeB[cell] + rank;
        const float x = pos[3 * gt], y = pos[3 * gt + 1], z = pos[3 * gt + 2];
        jt4s[dst] = make_float4(x, y, z, fmaf(x, x, fmaf(y, y, z * z)));
    }

    // --- my group's j-window end, straight from the in-LDS scan ---
    const int g = b >> 3, f = b & (F - 1);
    int jend;
    {
        const int p = (g + 1) * GSZ - 1;               // last sorted idx of group
        int lo = 0, hi = NBINS - 1;
        while (lo < hi) {                              // smallest c: incl[c] >= p+1
            const int mid = (lo + hi) >> 1;
            if (sm[mid] >= p + 1) hi = mid; else lo = mid + 1;
        }
        const int jidx = lo + MARGIN;
        jend = (jidx >= NBINS) ? N : sm[jidx - 1];     // excl[jidx]
    }

    // --- homebrew grid barrier: all jt4s writes visible everywhere ---
    __syncthreads();                       // drain this block's stores (vmcnt)
    if (t == 0) {
        __threadfence();                   // release: write back local L2
        __hip_atomic_fetch_add(bar, 1u, __ATOMIC_ACQ_REL, __HIP_MEMORY_SCOPE_AGENT);
        while (__hip_atomic_load(bar, __ATOMIC_ACQUIRE, __HIP_MEMORY_SCOPE_AGENT)
               < (unsigned int)NB) { }
        __threadfence();                   // acquire: invalidate stale L1/L2
    }
    __syncthreads();

    // --- pair sweep (R13 verbatim) ---
    const int gstart = g * GSZ;
    const int i0 = gstart + t;
    const float4 w0 = jt4s[i0];
    const float4 w1 = jt4s[i0 + BLOCK];

    const int jbeg = gstart + 1;
    const int jlen = jend - jbeg;                      // >= GSZ-1 always
    const int seg  = (((jlen + F - 1) / F) + QB - 1) & ~(QB - 1);  // QB-aligned
    const int j0   = jbeg + f * seg;
    const int len  = min(seg, jend - j0);              // > 0 for all f (jlen>=511)

    float xi2[IPT], yi2[IPT], zi2[IPT], sqi[IPT];
    xi2[0] = -2.0f * w0.x; yi2[0] = -2.0f * w0.y; zi2[0] = -2.0f * w0.z; sqi[0] = w0.w;
    xi2[1] = -2.0f * w1.x; yi2[1] = -2.0f * w1.y; zi2[1] = -2.0f * w1.z; sqi[1] = w1.w;

    float s = 0.0f;
    for (int cs = 0; cs < len; cs += CH) {             // 1 chunk for typical data
        const int clen = min(CH, len - cs);
        if (t < clen)         jsm[t]         = jt4s[j0 + cs + t];
        if (t + BLOCK < clen) jsm[t + BLOCK] = jt4s[j0 + cs + t + BLOCK];
        if (t < QB) jsm[clen + t] = make_float4(0.0f, 0.0f, 1.0e6f, 4.0e12f);
        __syncthreads();
        if (j0 + cs < gstart + GSZ)    // chunk may overlap own group: j>i mask
            s += cols<true >(jsm, clen, j0 + cs, i0, xi2, yi2, zi2, sqi);
        else
            s += cols<false>(jsm, clen, j0 + cs, i0, xi2, yi2, zi2, sqi);
        __syncthreads();               // before next chunk overwrites jsm
    }

    // reduce: wave shuffle -> LDS -> one atomic per block
    for (int off = 32; off > 0; off >>= 1) s += __shfl_down(s, off);
    if ((t & 63) == 0) wsum[t >> 6] = s;
    __syncthreads();
    if (t == 0) {
        float bs = 0.0f;
        #pragma unroll
        for (int w = 0; w < BLOCK / 64; ++w) bs += wsum[w];
        atomicAdd(acc, bs);
        __threadfence();
        const unsigned int done = atomicAdd(cnt, 1u);
        if (done == (unsigned int)(NB - 1)) {          // last block finalizes
            __threadfence();
            const float total = atomicAdd(acc, 0.0f);  // device-coherent read
            const double mean = 2.0 * (double)total / ((double)N * (double)N);
            out[(size_t)N * 3] = (float)(mean * 0.02);
        }
    }
}

extern "C" void kernel_launch(void* const* d_in, const int* in_sizes, int n_in,
                              void* d_out, int out_size, void* d_ws, size_t ws_size,
                              hipStream_t stream) {
    const float* pos = (const float*)d_in[0];
    float* out = (float*)d_out;
    // ws layout:
    //   0:      acc (float)   4: cnt (uint)   8: bar (uint)
    //   4096:   histPart[64][256]    (64 KiB)   -> ends 69632
    //   69632:  crk[16384] (uint)    (64 KiB)   -> ends 135168
    //   135168: jt4s[N x float4]     (256 KiB)
    float*        acc      = (float*)d_ws;
    unsigned int* cnt      = (unsigned int*)d_ws + 1;
    unsigned int* bar      = (unsigned int*)d_ws + 2;
    unsigned int* histPart = (unsigned int*)((char*)d_ws + 4096);
    unsigned int* crk      = (unsigned int*)((char*)d_ws + 69632);
    float4*       jt4s     = (float4*)((char*)d_ws + 135168);

    prep_kernel <<<NHB, BLOCK, 0, stream>>>(pos, out, histPart, crk, acc, cnt, bar);
    fused_kernel<<<NB,  BLOCK, 0, stream>>>(pos, histPart, crk, jt4s, bar, out, acc, cnt);
}

// Round 11
// 78.899 us; speedup vs baseline: 1.2264x; 1.2264x over previous
//
#include <hip/hip_runtime.h>

// StericClashConstraint: N=16384 pts [N,3] fp32.
// out[0..3N-1] = pos passthrough; out[3N] = mean(max(1-dist,0), diag=0) * 0.02
//
// Round 17: DE-RISK. R15/R16 (2-dispatch self-gather) hit "container failed
// twice" twice in a row; audit finds no kernel fault path (no spins, all
// indices bounded, 48KB LDS, static loops), but burning a third round on the
// same source is gambling. Revert to the PROVEN R13 3-dispatch structure
// (82.0us, passed, absmax=0.0) with one paper-provable improvement:
//   MARGIN 6 -> 5: cell=floor(4z) is exact in fp32 (x4 = exponent shift,
//   floor exact). Group's last point: z_last < (lo+1)/4-32 strictly.
//   Excluded j: cell_j >= lo+5 => z_j >= (lo+5)/4-32 => dz > 1.0 STRICTLY
//   => max(1-dist,0) = 0 exactly in both ref and kernel. ~12% fewer
//   pair-slots at the typical ~9-bin window.
// Everything else is R13 byte-for-byte:
//  k1 prep:    copy + per-block LDS z-hist -> partials; pack (cell, rank)
//              into crk (rank = LDS-atomic return); zero acc/cnt.
//  k2 scatter: 64 blocks EACH redundantly reduce the 64x256 partials +
//              Hillis-Steele scan in LDS, then dst = excl[cell]+
//              before_blk[cell]+rank -> NO global atomics. Block 0 writes
//              jendArr via binary search.
//  k3 pair:    256 fat blocks (1/CU), LDS-staged j-chunks, branchless
//              per-pair math (bit-identical since R8).
// Also the infra diagnostic: if THIS proven structure also container-fails,
// the node pool is broken, not the kernel.

constexpr int   N     = 16384;
constexpr int   BLOCK = 256;            // 4 waves
constexpr int   GSZ   = 512;            // i-group size
constexpr int   IPT   = GSZ / BLOCK;    // 2 i's per thread
constexpr int   NG    = N / GSZ;        // 32 i-groups
constexpr int   F     = 8;              // j-segments per group
constexpr int   NB    = NG * F;         // 256 pair blocks = 1/CU
constexpr int   QB    = 4;              // columns per unrolled chunk
constexpr int   NBINS = 256;            // z-bins, width 1/4, covering [-32,32)
constexpr float BINW_INV = 4.0f;        // *4 exact in fp32
constexpr int   MARGIN = 5;             // cell_j >= cell_last+5 => dz > 1.0 strict
constexpr int   CH    = 288;            // columns staged per LDS chunk
constexpr int   NHB   = N / BLOCK;      // 64 blocks own the points

__device__ __forceinline__ int zcell(float z) {
    int c = (int)floorf(z * BINW_INV) + NBINS / 2;
    return min(max(c, 0), NBINS - 1);
}

// ---- k1: passthrough + per-block partial hist + (cell,rank) pack -----------
__global__ void __launch_bounds__(BLOCK)
prep_kernel(const float* __restrict__ pos, float* __restrict__ out,
            unsigned int* __restrict__ histPart, unsigned int* __restrict__ crk,
            float* __restrict__ acc, unsigned int* __restrict__ cnt) {
    __shared__ unsigned int lh[NBINS];
    const int b = blockIdx.x, t = threadIdx.x;
    const int gt = b * BLOCK + t;                     // 0..16383
    lh[t] = 0u;                                       // NBINS == BLOCK
    if (gt == 0) { *acc = 0.0f; *cnt = 0u; }          // replaces memset dispatch
    __syncthreads();
    if (gt < (N * 3) / 4) {
        reinterpret_cast<float4*>(out)[gt] = reinterpret_cast<const float4*>(pos)[gt];
    }
    const float z = pos[3 * gt + 2];
    const int cell = zcell(z);
    const unsigned int rank = atomicAdd(&lh[cell], 1u);   // rank in (block,cell)
    crk[gt] = (unsigned int)cell | (rank << 16);
    __syncthreads();
    histPart[b * NBINS + t] = lh[t];
}

// ---- k2: redundant scan per block + atomic-free scatter + jendArr ----------
__global__ void __launch_bounds__(BLOCK)
scatter_kernel(const float* __restrict__ pos, const unsigned int* __restrict__ histPart,
               const unsigned int* __restrict__ crk, float4* __restrict__ jt4s,
               int* __restrict__ jendArr) {
    __shared__ int sm[NBINS];
    __shared__ int beforeB[NBINS];
    const int b = blockIdx.x, t = threadIdx.x;        // 64 blocks x 256
    int v = 0, bef = 0;
    #pragma unroll 8
    for (int p = 0; p < NHB; ++p) {                   // coalesced L2 reads
        const int hv = (int)histPart[p * NBINS + t];
        if (p == b) bef = v;                          // sum over blocks < b
        v += hv;
    }
    sm[t] = v; beforeB[t] = bef;
    __syncthreads();
    for (int off = 1; off < NBINS; off <<= 1) {       // Hillis-Steele inclusive
        const int a = (t >= off) ? sm[t - off] : 0;
        __syncthreads();
        sm[t] += a;
        __syncthreads();
    }
    // scatter own 256 points, no atomics
    const int gt = b * BLOCK + t;
    const unsigned int cr = crk[gt];
    const int cell = (int)(cr & 0xffffu);
    const int rank = (int)(cr >> 16);
    const int ex   = (cell > 0) ? sm[cell - 1] : 0;
    const int dst  = ex + beforeB[cell] + rank;
    const float x = pos[3 * gt], y = pos[3 * gt + 1], z = pos[3 * gt + 2];
    jt4s[dst] = make_float4(x, y, z, fmaf(x, x, fmaf(y, y, z * z)));
    // block 0: per-group j-window ends
    if (b == 0 && t < NG) {
        const int p = (t + 1) * GSZ - 1;              // last sorted idx of group
        int lo = 0, hi = NBINS - 1;
        while (lo < hi) {                             // smallest c: incl[c] >= p+1
            const int mid = (lo + hi) >> 1;
            if (sm[mid] >= p + 1) hi = mid; else lo = mid + 1;
        }
        const int jidx = lo + MARGIN;
        jendArr[t] = (jidx >= NBINS) ? N : sm[jidx - 1];   // excl[jidx]
    }
}

// ---- k3: pruned pair sweep (R13 verbatim) ----------------------------------
template <bool MASKED>
__device__ __forceinline__ float cols(const float4* __restrict__ jsm,
                                      int clen, int jbase, int i0,
                                      const float (&xi2)[IPT], const float (&yi2)[IPT],
                                      const float (&zi2)[IPT], const float (&sqi)[IPT]) {
    float s = 0.0f;
    for (int c = 0; c < clen; c += QB) {              // sentinel pad covers overrun
        #pragma unroll
        for (int u = 0; u < QB; ++u) {
            const float4 pj = jsm[c + u];             // uniform addr -> broadcast
            const int jq = jbase + c + u;
            #pragma unroll
            for (int k = 0; k < IPT; ++k) {
                float d = fmaf(xi2[k], pj.x, pj.w);
                d = fmaf(yi2[k], pj.y, d);
                d = fmaf(zi2[k], pj.z, d);                     // sq_j - 2*dot
                const float d2 = fmaxf(d + sqi[k], 0.0f);      // + sq_i, clamp
                float w = 1.0f - __builtin_amdgcn_sqrtf(d2);   // 1 - dist
                w = fmaxf(w, 0.0f);                            // clamp(min=0)
                if (MASKED) w = (jq > i0 + k * BLOCK) ? w : 0.0f;   // j>i only
                s += w;
            }
        }
    }
    return s;
}

__global__ void __launch_bounds__(BLOCK)
pair_kernel(const float4* __restrict__ jt4s, const int* __restrict__ jendArr,
            float* __restrict__ out, float* __restrict__ acc,
            unsigned int* __restrict__ cnt) {
    __shared__ float4 jsm[CH + QB];
    __shared__ float wsum[BLOCK / 64];
    const int b = blockIdx.x;
    const int t = threadIdx.x;
    const int g = b >> 3, f = b & (F - 1);
    const int gstart = g * GSZ;
    const int i0 = gstart + t;

    // issue i-fragment loads first (overlap with jend load + param math)
    const float4 w0 = jt4s[i0];
    const float4 w1 = jt4s[i0 + BLOCK];

    const int jend = jendArr[g];                       // one scalar load
    const int jbeg = gstart + 1;
    const int jlen = jend - jbeg;                      // >= GSZ-1 always
    const int seg  = (((jlen + F - 1) / F) + QB - 1) & ~(QB - 1);  // QB-aligned
    const int j0   = jbeg + f * seg;
    const int len  = min(seg, jend - j0);              // > 0 for all f (jlen>=511)

    float xi2[IPT], yi2[IPT], zi2[IPT], sqi[IPT];
    xi2[0] = -2.0f * w0.x; yi2[0] = -2.0f * w0.y; zi2[0] = -2.0f * w0.z; sqi[0] = w0.w;
    xi2[1] = -2.0f * w1.x; yi2[1] = -2.0f * w1.y; zi2[1] = -2.0f * w1.z; sqi[1] = w1.w;

    float s = 0.0f;
    for (int cs = 0; cs < len; cs += CH) {             // 1 chunk for typical data
        const int clen = min(CH, len - cs);
        if (t < clen)         jsm[t]         = jt4s[j0 + cs + t];
        if (t + BLOCK < clen) jsm[t + BLOCK] = jt4s[j0 + cs + t + BLOCK];
        if (t < QB) jsm[clen + t] = make_float4(0.0f, 0.0f, 1.0e6f, 4.0e12f);
        __syncthreads();
        if (j0 + cs < gstart + GSZ)    // chunk may overlap own group: j>i mask
            s += cols<true >(jsm, clen, j0 + cs, i0, xi2, yi2, zi2, sqi);
        else
            s += cols<false>(jsm, clen, j0 + cs, i0, xi2, yi2, zi2, sqi);
        __syncthreads();               // before next chunk overwrites jsm
    }

    // reduce: wave shuffle -> LDS -> one atomic per block
    for (int off = 32; off > 0; off >>= 1) s += __shfl_down(s, off);
    if ((t & 63) == 0) wsum[t >> 6] = s;
    __syncthreads();
    if (t == 0) {
        float bs = 0.0f;
        #pragma unroll
        for (int w = 0; w < BLOCK / 64; ++w) bs += wsum[w];
        atomicAdd(acc, bs);
        __threadfence();
        const unsigned int done = atomicAdd(cnt, 1u);
        if (done == (unsigned int)(NB - 1)) {          // last block finalizes
            __threadfence();
            const float total = atomicAdd(acc, 0.0f);  // device-coherent read
            const double mean = 2.0 * (double)total / ((double)N * (double)N);
            out[(size_t)N * 3] = (float)(mean * 0.02);
        }
    }
}

extern "C" void kernel_launch(void* const* d_in, const int* in_sizes, int n_in,
                              void* d_out, int out_size, void* d_ws, size_t ws_size,
                              hipStream_t stream) {
    const float* pos = (const float*)d_in[0];
    float* out = (float*)d_out;
    // ws layout:
    //   0:      acc (float)      4: cnt (uint)
    //   256:    jendArr[32]          (128 B)
    //   4096:   histPart[64][256]    (64 KiB)   -> ends 69632
    //   69632:  crk[16384] (uint)    (64 KiB)   -> ends 135168
    //   135168: jt4s[N x float4]     (256 KiB)
    float*        acc      = (float*)d_ws;
    unsigned int* cnt      = (unsigned int*)d_ws + 1;
    int*          jendArr  = (int*)((char*)d_ws + 256);
    unsigned int* histPart = (unsigned int*)((char*)d_ws + 4096);
    unsigned int* crk      = (unsigned int*)((char*)d_ws + 69632);
    float4*       jt4s     = (float4*)((char*)d_ws + 135168);

    prep_kernel   <<<NHB, BLOCK, 0, stream>>>(pos, out, histPart, crk, acc, cnt);
    scatter_kernel<<<NHB, BLOCK, 0, stream>>>(pos, histPart, crk, jt4s, jendArr);
    pair_kernel   <<<NB,  BLOCK, 0, stream>>>(jt4s, jendArr, out, acc, cnt);
}